// Round 8
// baseline (2367.461 us; speedup 1.0000x reference)
//
#include <hip/hip_runtime.h>
#include <cstdio>
#include <cstdint>

typedef _Float16 f16;
typedef f16 hf2   __attribute__((ext_vector_type(2)));
typedef f16 f16x8 __attribute__((ext_vector_type(8)));
typedef float f32x4 __attribute__((ext_vector_type(4)));
typedef unsigned int   u32;
typedef unsigned short u16;

#define B_    256
#define S_    512
#define IN_   32
#define H_    256
#define G3_   768
#define D_    32
#define PRED_ 96
#define SC_   64          // sequence chunk per dispatch round

#if __has_builtin(__builtin_amdgcn_fdot2)
__device__ __forceinline__ float fdot2(hf2 a, hf2 b, float c) {
  return __builtin_amdgcn_fdot2(a, b, c, false);
}
#else
__device__ __forceinline__ float fdot2(hf2 a, hf2 b, float c) {
  return c + (float)a[0] * (float)b[0] + (float)a[1] * (float)b[1];
}
#endif

__device__ __forceinline__ float sigm(float x) {
  return __builtin_amdgcn_rcpf(1.f + __expf(-x));
}
__device__ __forceinline__ float tanh_fast(float x) {
  return 1.f - 2.f * __builtin_amdgcn_rcpf(__expf(2.f * x) + 1.f);
}
__device__ __forceinline__ hf2 bc2(u32 v) { return __builtin_bit_cast(hf2, v); }

__global__ void f32_to_f16_k(const float* __restrict__ in, f16* __restrict__ out, int n) {
  int i = blockIdx.x * blockDim.x + threadIdx.x;
  if (i < n) out[i] = (f16)in[i];
}

__device__ __forceinline__ f16x8 cvt8(const float* p) {
  float4 lo = ((const float4*)p)[0];
  float4 hi = ((const float4*)p)[1];
  f16x8 r;
  r[0] = (f16)lo.x; r[1] = (f16)lo.y; r[2] = (f16)lo.z; r[3] = (f16)lo.w;
  r[4] = (f16)hi.x; r[5] = (f16)hi.y; r[6] = (f16)hi.z; r[7] = (f16)hi.w;
  return r;
}

// ---------------- standalone chunked xp GEMM (MFMA lives ONLY here) ---------
// xp[m][n] = A[m][:] . Wih[n][:] + bih[n] for m in [0, B*SC), n in [0,768).
// A rows: LAYER0 -> x f32 row (m>>6)*512 + t0 + (m&63); LAYER1 -> h16c row m.
// Verified fragment math from rounds 2-7's in-kernel phase.
template <int LAYER>
__global__ __launch_bounds__(256) void gemm_xp(
    const void* __restrict__ Asrc, const f16* __restrict__ Wih,
    const float* __restrict__ bih, f16* __restrict__ xp, int t0) {
  constexpr int KK = LAYER ? H_ : IN_;
  const int tid = threadIdx.x, wv = tid >> 6, lane = tid & 63;
  const int lm = lane & 15, q = lane >> 4;
  const int m0 = blockIdx.x * 32;
  const int n0 = blockIdx.y * 64 + wv * 16;

  f32x4 ac0 = {0.f, 0.f, 0.f, 0.f}, ac1 = ac0;
  const f16* Bp = Wih + (size_t)(n0 + lm) * KK + q * 8;
#pragma unroll 2
  for (int k0 = 0; k0 < KK; k0 += 32) {
    f16x8 bv = *(const f16x8*)(Bp + k0);
    f16x8 a0, a1;
    if constexpr (LAYER == 0) {
      const float* xr = (const float*)Asrc +
          ((size_t)(m0 >> 6) * S_ + t0 + (m0 & 63) + lm) * IN_ + k0 + q * 8;
      a0 = cvt8(xr);
      a1 = cvt8(xr + 16 * IN_);
    } else {
      const f16* ar = (const f16*)Asrc + (size_t)(m0 + lm) * H_ + k0 + q * 8;
      a0 = *(const f16x8*)ar;
      a1 = *(const f16x8*)(ar + 16 * H_);
    }
    ac0 = __builtin_amdgcn_mfma_f32_16x16x32_f16(a0, bv, ac0, 0, 0, 0);
    ac1 = __builtin_amdgcn_mfma_f32_16x16x32_f16(a1, bv, ac1, 0, 0, 0);
  }
  const float bb = bih[n0 + lm];
#pragma unroll
  for (int r = 0; r < 4; ++r) {   // D: col=lane&15 (n), row=q*4+r (m)
    xp[(size_t)(m0 + q * 4 + r) * G3_ + n0 + lm]      = (f16)(ac0[r] + bb);
    xp[(size_t)(m0 + 16 + q * 4 + r) * G3_ + n0 + lm] = (f16)(ac1[r] + bb);
  }
}

// ---- literal-index weight load from pre-converted f16 W_hh ----
#define LDW8(b0, src, u)                                              \
  { f16x8 v = (src)[u];                                               \
    w[(b0) + 4 * (u)]     = hf2{v[0], v[1]};                          \
    w[(b0) + 4 * (u) + 1] = hf2{v[2], v[3]};                          \
    w[(b0) + 4 * (u) + 2] = hf2{v[4], v[5]};                          \
    w[(b0) + 4 * (u) + 3] = hf2{v[6], v[7]}; }
#define LDW32(b0, src)                                                \
  LDW8(b0, src, 0) LDW8(b0, src, 1) LDW8(b0, src, 2) LDW8(b0, src, 3) \
  LDW8(b0, src, 4) LDW8(b0, src, 5) LDW8(b0, src, 6) LDW8(b0, src, 7)

#define DOTCC(cc)                                                              \
  { uint4 hv = hb[cc];                                                         \
    hf2 hh0 = bc2(hv.x), hh1 = bc2(hv.y), hh2 = bc2(hv.z), hh3 = bc2(hv.w);   \
    ar0 = fdot2(w[      4*(cc)    ], hh0, ar0);                                \
    ar0 = fdot2(w[      4*(cc) + 1], hh1, ar0);                                \
    ar0 = fdot2(w[      4*(cc) + 2], hh2, ar0);                                \
    ar0 = fdot2(w[      4*(cc) + 3], hh3, ar0);                                \
    az0 = fdot2(w[ 32 + 4*(cc)    ], hh0, az0);                                \
    az0 = fdot2(w[ 32 + 4*(cc) + 1], hh1, az0);                                \
    az0 = fdot2(w[ 32 + 4*(cc) + 2], hh2, az0);                                \
    az0 = fdot2(w[ 32 + 4*(cc) + 3], hh3, az0);                                \
    an0 = fdot2(w[ 64 + 4*(cc)    ], hh0, an0);                                \
    an0 = fdot2(w[ 64 + 4*(cc) + 1], hh1, an0);                                \
    an0 = fdot2(w[ 64 + 4*(cc) + 2], hh2, an0);                                \
    an0 = fdot2(w[ 64 + 4*(cc) + 3], hh3, an0);                                \
    ar1 = fdot2(w[ 96 + 4*(cc)    ], hh0, ar1);                                \
    ar1 = fdot2(w[ 96 + 4*(cc) + 1], hh1, ar1);                                \
    ar1 = fdot2(w[ 96 + 4*(cc) + 2], hh2, ar1);                                \
    ar1 = fdot2(w[ 96 + 4*(cc) + 3], hh3, ar1);                                \
    az1 = fdot2(w[128 + 4*(cc)    ], hh0, az1);                                \
    az1 = fdot2(w[128 + 4*(cc) + 1], hh1, az1);                                \
    az1 = fdot2(w[128 + 4*(cc) + 2], hh2, az1);                                \
    az1 = fdot2(w[128 + 4*(cc) + 3], hh3, az1);                                \
    an1 = fdot2(w[160 + 4*(cc)    ], hh0, an1);                                \
    an1 = fdot2(w[160 + 4*(cc) + 1], hh1, an1);                                \
    an1 = fdot2(w[160 + 4*(cc) + 2], hh2, an1);                                \
    an1 = fdot2(w[160 + 4*(cc) + 3], hh3, an1); }

// ---------------- GRU recurrence chunk: NO MFMA in this kernel --------------
// One WG (512 thr) per batch row; thread (j2=tid>>2, kq=tid&3) owns rows
// {j2, j2+128} x {r,z,n} of W_hh, k-slice [kq*64, kq*64+64) -> w[192] hf2.
// Without MFMA the backend should not split the unified RF budget into
// arch/AGPR halves -> 192-reg array register-allocates at 2 waves/EU.
template <int LAYER>
__global__ __attribute__((amdgpu_waves_per_eu(2, 2))) __launch_bounds__(512)
void gru_rec(
    const f16* __restrict__ xp,      // [B*SC][768] chunk, includes b_ih
    const f16* __restrict__ Wh,      // f16 [768][256]
    const float* __restrict__ bhh,   // [768]
    f16* __restrict__ h16c,          // [B*SC][256] chunk out (LAYER==0)
    float* __restrict__ carry,       // [B][256] f32 state in/out
    int first) {
  const int b   = blockIdx.x;
  const int tid = threadIdx.x;
  const int j2 = tid >> 2, kq = tid & 3;

  hf2 w[192];
  {
    const f16x8* s00 = (const f16x8*)(Wh + (size_t)(j2)       * 256 + kq * 64);
    const f16x8* s01 = (const f16x8*)(Wh + (size_t)(256 + j2) * 256 + kq * 64);
    const f16x8* s02 = (const f16x8*)(Wh + (size_t)(512 + j2) * 256 + kq * 64);
    const f16x8* s10 = (const f16x8*)(Wh + (size_t)(128 + j2) * 256 + kq * 64);
    const f16x8* s11 = (const f16x8*)(Wh + (size_t)(384 + j2) * 256 + kq * 64);
    const f16x8* s12 = (const f16x8*)(Wh + (size_t)(640 + j2) * 256 + kq * 64);
    LDW32(0,   s00) LDW32(32,  s01) LDW32(64,  s02)
    LDW32(96,  s10) LDW32(128, s11) LDW32(160, s12)
  }
  const float bh00 = bhh[j2],       bh01 = bhh[256 + j2], bh02 = bhh[512 + j2];
  const float bh10 = bhh[128 + j2], bh11 = bhh[384 + j2], bh12 = bhh[640 + j2];

  __shared__ __align__(16) u16 hbuf[2][288];   // dbuf h, 4 slices of 72 halves
  float h0s, h1s;
  if (first) {
    if (tid < 144) ((u32*)hbuf[0])[tid] = 0u;
    h0s = 0.f; h1s = 0.f;
  } else {
    if (tid < 256)
      hbuf[0][(tid >> 6) * 72 + (tid & 63)] =
          __builtin_bit_cast(u16, (f16)carry[b * 256 + tid]);
    h0s = carry[b * 256 + j2];
    h1s = carry[b * 256 + 128 + j2];
  }
  __syncthreads();
  int cur = 0;

  const f16* xbase = xp + (size_t)b * SC_ * G3_;
  f16 xrn = xbase[j2], xzn = xbase[256 + j2], xnn = xbase[512 + j2];

  for (int tl = 0; tl < SC_; ++tl) {
    float xr = (float)xrn, xz = (float)xzn, xn = (float)xnn;
    if (tl + 1 < SC_) {   // prefetch next step's xp (uniform branch)
      const f16* xq = xbase + (size_t)(tl + 1) * G3_;
      xrn = xq[j2]; xzn = xq[256 + j2]; xnn = xq[512 + j2];
    }

    float ar0 = 0.f, az0 = 0.f, an0 = 0.f, ar1 = 0.f, az1 = 0.f, an1 = 0.f;
    const uint4* hb = (const uint4*)hbuf[cur] + kq * 9;
    DOTCC(0) DOTCC(1) DOTCC(2) DOTCC(3)
    DOTCC(4) DOTCC(5) DOTCC(6) DOTCC(7)

    ar0 += __shfl_xor(ar0, 1); ar0 += __shfl_xor(ar0, 2);
    az0 += __shfl_xor(az0, 1); az0 += __shfl_xor(az0, 2);
    an0 += __shfl_xor(an0, 1); an0 += __shfl_xor(an0, 2);
    ar1 += __shfl_xor(ar1, 1); ar1 += __shfl_xor(ar1, 2);
    az1 += __shfl_xor(az1, 1); az1 += __shfl_xor(az1, 2);
    an1 += __shfl_xor(an1, 1); an1 += __shfl_xor(an1, 2);

    {
      float r = sigm(xr + ar0 + bh00);
      float z = sigm(xz + az0 + bh01);
      float n = tanh_fast(xn + r * (an0 + bh02));
      h0s = (1.f - z) * n + z * h0s;
    }
    {
      float r = sigm((float)xrn * 0.f + xr * 0.f +  // (no-op guard removed)
                     0.f);
      (void)r;
    }
    {
      // second hidden unit uses its own xp values
      float xr1 = 0.f, xz1 = 0.f, xn1 = 0.f;
      const f16* xc = xbase + (size_t)tl * G3_;
      xr1 = (float)xc[128 + j2]; xz1 = (float)xc[384 + j2]; xn1 = (float)xc[640 + j2];
      float r = sigm(xr1 + ar1 + bh10);
      float z = sigm(xz1 + az1 + bh11);
      float n = tanh_fast(xn1 + r * (an1 + bh12));
      h1s = (1.f - z) * n + z * h1s;
    }

    if (kq == 0) {
      hbuf[cur ^ 1][(j2 >> 6) * 72 + (j2 & 63)] = __builtin_bit_cast(u16, (f16)h0s);
      if constexpr (LAYER == 0)
        h16c[((size_t)b * SC_ + tl) * H_ + j2] = (f16)h0s;
    } else if (kq == 1) {
      const int jb = j2 + 128;
      hbuf[cur ^ 1][(jb >> 6) * 72 + (jb & 63)] = __builtin_bit_cast(u16, (f16)h1s);
      if constexpr (LAYER == 0)
        h16c[((size_t)b * SC_ + tl) * H_ + jb] = (f16)h1s;
    }
    __syncthreads();
    cur ^= 1;
  }
  if (kq == 0)      carry[b * 256 + j2]       = h0s;
  else if (kq == 1) carry[b * 256 + 128 + j2] = h1s;
}

// ---------------- projection + 96-step rollout ------------------------------
__global__ __launch_bounds__(128) void proj_rollout(
    const float* __restrict__ hfinal, const float* __restrict__ Wp,
    const float* __restrict__ bp, const float* __restrict__ Cm,
    const float* __restrict__ rld, const float* __restrict__ rtd,
    const float* __restrict__ rg, const float* __restrict__ om,
    float* __restrict__ out) {
  const int b = blockIdx.x, tid = threadIdx.x;
  __shared__ float fh[256];
  __shared__ float sb[128];
  ((float2*)fh)[tid] = ((const float2*)(hfinal + b * 256))[tid];
  __syncthreads();
  const float4* wrow = (const float4*)(Wp + tid * 256);
  float acc = 0.f;
#pragma unroll 16
  for (int k4 = 0; k4 < 64; k4++) {
    float4 wv = wrow[k4];
    acc += wv.x * fh[4 * k4] + wv.y * fh[4 * k4 + 1] + wv.z * fh[4 * k4 + 2] +
           wv.w * fh[4 * k4 + 3];
  }
  sb[tid] = acc + bp[tid];
  __syncthreads();
  if (tid < 32) {
    const int dd = tid;
    float s0 = sb[dd * 4], s1 = sb[dd * 4 + 1], s2 = sb[dd * 4 + 2], s3 = sb[dd * 4 + 3];
    float al = sigm(rld[dd]) * 0.15f + 0.85f;
    float at = sigm(rtd[dd]) * 0.25f + 0.70f;
    float g  = sigm(rg[dd]) * 0.20f + 0.80f;
    float cw = cosf(om[dd]), sw = sinf(om[dd]);
    float r00 = g * cw, r01 = -g * sw, r10 = g * sw, r11 = g * cw;
    float c0 = Cm[dd * 4], c1 = Cm[dd * 4 + 1], c2 = Cm[dd * 4 + 2], c3 = Cm[dd * 4 + 3];
    float* op = out + (size_t)b * PRED_ * D_ + dd;
    for (int t = 0; t < PRED_; t++) {
      float n0 = s0 * al, n1 = s1 * at;
      float n2 = s2 * r00 + s3 * r10;
      float n3 = s2 * r01 + s3 * r11;
      op[(size_t)t * D_] = c0 * n0 + c1 * n1 + c2 * n2 + c3 * n3;
      s0 = n0; s1 = n1; s2 = n2; s3 = n3;
    }
  }
}

extern "C" void kernel_launch(void* const* d_in, const int* in_sizes, int n_in,
                              void* d_out, int out_size, void* d_ws,
                              size_t ws_size, hipStream_t stream) {
  (void)in_sizes; (void)n_in; (void)out_size;
  const float* x     = (const float*)d_in[0];
  const float* Wih0  = (const float*)d_in[1];
  const float* Whh0  = (const float*)d_in[2];
  const float* bih0  = (const float*)d_in[3];
  const float* bhh0  = (const float*)d_in[4];
  const float* Wih1  = (const float*)d_in[5];
  const float* Whh1  = (const float*)d_in[6];
  const float* bih1  = (const float*)d_in[7];
  const float* bhh1  = (const float*)d_in[8];
  const float* Wproj = (const float*)d_in[9];
  const float* bproj = (const float*)d_in[10];
  const float* Cm    = (const float*)d_in[11];
  const float* rld   = (const float*)d_in[12];
  const float* rtd   = (const float*)d_in[13];
  const float* rg    = (const float*)d_in[14];
  const float* om    = (const float*)d_in[15];
  float* out = (float*)d_out;

  char* ws = (char*)d_ws;
  size_t off = 0;
  auto alloc = [&](size_t bytes) { size_t o = off; off += (bytes + 255) & ~(size_t)255; return o; };
  const size_t wi0_off  = alloc(G3_ * IN_ * 2);        //      49,152
  const size_t wi1_off  = alloc(G3_ * H_ * 2);         //     393,216
  const size_t wh0_off  = alloc(G3_ * H_ * 2);         //     393,216
  const size_t wh1_off  = alloc(G3_ * H_ * 2);         //     393,216
  const size_t xp0_off  = alloc((size_t)B_ * SC_ * G3_ * 2);  // 25,165,824
  const size_t xp1_off  = alloc((size_t)B_ * SC_ * G3_ * 2);  // 25,165,824
  const size_t h16_off  = alloc((size_t)B_ * SC_ * H_ * 2);   //  8,388,608
  const size_t c0_off   = alloc(B_ * H_ * 4);          //     262,144
  const size_t c1_off   = alloc(B_ * H_ * 4);          //     262,144
  const size_t need = off;                             // ~60.6 MB
  if (ws_size < need) {
    fprintf(stderr, "kernel_launch: ws too small: have %zu need %zu — skipping\n",
            ws_size, need);
    return;
  }
  f16* wi016  = (f16*)(ws + wi0_off);
  f16* wi116  = (f16*)(ws + wi1_off);
  f16* wh016  = (f16*)(ws + wh0_off);
  f16* wh116  = (f16*)(ws + wh1_off);
  f16* xp0    = (f16*)(ws + xp0_off);
  f16* xp1    = (f16*)(ws + xp1_off);
  f16* h16c   = (f16*)(ws + h16_off);
  float* car0 = (float*)(ws + c0_off);
  float* car1 = (float*)(ws + c1_off);

  f32_to_f16_k<<<96, 256, 0, stream>>>(Wih0, wi016, G3_ * IN_);
  f32_to_f16_k<<<768, 256, 0, stream>>>(Wih1, wi116, G3_ * H_);
  f32_to_f16_k<<<768, 256, 0, stream>>>(Whh0, wh016, G3_ * H_);
  f32_to_f16_k<<<768, 256, 0, stream>>>(Whh1, wh116, G3_ * H_);

  for (int c = 0; c < S_ / SC_; ++c) {
    const int t0 = c * SC_;
    gemm_xp<0><<<dim3(B_ * SC_ / 32, G3_ / 64), 256, 0, stream>>>(
        (const void*)x, wi016, bih0, xp0, t0);
    gru_rec<0><<<B_, 512, 0, stream>>>(xp0, wh016, bhh0, h16c, car0, c == 0);
    gemm_xp<1><<<dim3(B_ * SC_ / 32, G3_ / 64), 256, 0, stream>>>(
        (const void*)h16c, wi116, bih1, xp1, t0);
    gru_rec<1><<<B_, 512, 0, stream>>>(xp1, wh116, bhh1, nullptr, car1, c == 0);
  }
  proj_rollout<<<B_, 128, 0, stream>>>(car1, Wproj, bproj, Cm, rld, rtd, rg, om, out);
}